// Round 19
// baseline (502.266 us; speedup 1.0000x reference)
//
#include <hip/hip_runtime.h>
#include <stdint.h>

typedef __bf16 bf16_t;
typedef __bf16 bf16x8 __attribute__((ext_vector_type(8)));
typedef __bf16 bf16x4 __attribute__((ext_vector_type(4)));
typedef __bf16 bf16x2 __attribute__((ext_vector_type(2)));
typedef float f32x4 __attribute__((ext_vector_type(4)));

#define S_LEN 2048
#define NH 32
#define NKV 8
#define HD 128
#define B_SZ 2
#define HID 4096
#define QKV_N 6144
#define INFF __builtin_inff()
// 1/sqrt(128) * log2(e): Q pre-scaled so softmax uses exp2 directly
#define QSCALE (0.08838834764831845f * 1.4426950408889634f)

// global -> LDS direct copy, 16B per lane. LDS dest must be wave-uniform base + lane*16.
__device__ __forceinline__ void gload_lds16(const void* g, void* l) {
    __builtin_amdgcn_global_load_lds(
        (const __attribute__((address_space(1))) void*)(uintptr_t)g,
        (__attribute__((address_space(3))) void*)(uint32_t)(uintptr_t)l,
        16, 0, 0);
}

// ---------------- fp32 -> bf16 convert, 5 sources -> contiguous dst ----------------
__global__ __launch_bounds__(256) void f2b5(const float4* __restrict__ s0,
                                            const float4* __restrict__ s1,
                                            const float4* __restrict__ s2,
                                            const float4* __restrict__ s3,
                                            const float4* __restrict__ s4,
                                            bf16x4* __restrict__ dst,
                                            int c0, int c1, int c2, int c3, int c4) {
    int i = blockIdx.x * blockDim.x + threadIdx.x;
    if (i >= c4) return;
    const float4* s; int j;
    if (i < c0)      { s = s0; j = i; }
    else if (i < c1) { s = s1; j = i - c0; }
    else if (i < c2) { s = s2; j = i - c1; }
    else if (i < c3) { s = s3; j = i - c2; }
    else             { s = s4; j = i - c3; }
    float4 v = s[j];
    bf16x4 o = {(bf16_t)v.x, (bf16_t)v.y, (bf16_t)v.z, (bf16_t)v.w};
    dst[i] = o;
}

// ---------------- GEMM 256x256 tile, 8-wave ----------------
#define SLOT_E 16384   // elems per slot (A 8192 + B 8192) = 32KB

// ring-4 tile (WO GEMM): counted vmcnt(8), 128KB LDS, 1 block/CU
#define GTILE(T, STAGE, VMW) do {                                                         \
    const int _sb = ((T) & 3) * SLOT_E;                                                   \
    const int _ss = (((T) + 3) & 3) * SLOT_E;                                             \
    bf16x8 af[8], bfr[2], bfs[2];                                                         \
    _Pragma("unroll") for (int i = 0; i < 8; ++i)                                         \
        af[i] = *(const bf16x8*)&lds[_sb + offA[i]];                                      \
    bfr[0] = *(const bf16x8*)&lds[_sb + 8192 + offB[0]];                                  \
    bfr[1] = *(const bf16x8*)&lds[_sb + 8192 + offB[1]];                                  \
    if (STAGE) {                                                                          \
        gload_lds16(sA0, &lds[_ss + ldsO0]); gload_lds16(sA1, &lds[_ss + ldsO1]);         \
        sA0 += 32; sA1 += 32;                                                             \
    }                                                                                     \
    __builtin_amdgcn_s_setprio(1);                                                        \
    _Pragma("unroll") for (int i = 0; i < 8; ++i) {                                       \
        acc[i][0] = __builtin_amdgcn_mfma_f32_16x16x32_bf16(af[i], bfr[0], acc[i][0], 0, 0, 0); \
        acc[i][1] = __builtin_amdgcn_mfma_f32_16x16x32_bf16(af[i], bfr[1], acc[i][1], 0, 0, 0); \
    }                                                                                     \
    __builtin_amdgcn_s_setprio(0);                                                        \
    bfs[0] = *(const bf16x8*)&lds[_sb + 8192 + offB[2]];                                  \
    bfs[1] = *(const bf16x8*)&lds[_sb + 8192 + offB[3]];                                  \
    if (STAGE) {                                                                          \
        gload_lds16(sB0, &lds[_ss + 8192 + ldsO0]); gload_lds16(sB1, &lds[_ss + 8192 + ldsO1]); \
        sB0 += 32; sB1 += 32;                                                             \
    }                                                                                     \
    __builtin_amdgcn_s_setprio(1);                                                        \
    _Pragma("unroll") for (int i = 0; i < 8; ++i) {                                       \
        acc[i][2] = __builtin_amdgcn_mfma_f32_16x16x32_bf16(af[i], bfs[0], acc[i][2], 0, 0, 0); \
        acc[i][3] = __builtin_amdgcn_mfma_f32_16x16x32_bf16(af[i], bfs[1], acc[i][3], 0, 0, 0); \
    }                                                                                     \
    __builtin_amdgcn_s_setprio(0);                                                        \
    if ((VMW) == 8)      asm volatile("s_waitcnt vmcnt(8)" ::: "memory");                 \
    else if ((VMW) == 4) asm volatile("s_waitcnt vmcnt(4)" ::: "memory");                 \
    else if ((VMW) == 0) asm volatile("s_waitcnt vmcnt(0)" ::: "memory");                 \
    __builtin_amdgcn_s_barrier();                                                         \
} while (0)

// ring-2 tile (QKV GEMM): dbuf, 64KB LDS, 2 blocks/CU — drain covered by partner block
#define GTILE2(T, STAGE) do {                                                             \
    const int _sb = ((T) & 1) * SLOT_E;                                                   \
    const int _ss = _sb ^ SLOT_E;                                                         \
    bf16x8 af[8], bfr[2], bfs[2];                                                         \
    _Pragma("unroll") for (int i = 0; i < 8; ++i)                                         \
        af[i] = *(const bf16x8*)&lds[_sb + offA[i]];                                      \
    bfr[0] = *(const bf16x8*)&lds[_sb + 8192 + offB[0]];                                  \
    bfr[1] = *(const bf16x8*)&lds[_sb + 8192 + offB[1]];                                  \
    if (STAGE) {                                                                          \
        gload_lds16(sA0, &lds[_ss + ldsO0]); gload_lds16(sA1, &lds[_ss + ldsO1]);         \
        sA0 += 32; sA1 += 32;                                                             \
    }                                                                                     \
    __builtin_amdgcn_s_setprio(1);                                                        \
    _Pragma("unroll") for (int i = 0; i < 8; ++i) {                                       \
        acc[i][0] = __builtin_amdgcn_mfma_f32_16x16x32_bf16(af[i], bfr[0], acc[i][0], 0, 0, 0); \
        acc[i][1] = __builtin_amdgcn_mfma_f32_16x16x32_bf16(af[i], bfr[1], acc[i][1], 0, 0, 0); \
    }                                                                                     \
    __builtin_amdgcn_s_setprio(0);                                                        \
    bfs[0] = *(const bf16x8*)&lds[_sb + 8192 + offB[2]];                                  \
    bfs[1] = *(const bf16x8*)&lds[_sb + 8192 + offB[3]];                                  \
    if (STAGE) {                                                                          \
        gload_lds16(sB0, &lds[_ss + 8192 + ldsO0]); gload_lds16(sB1, &lds[_ss + 8192 + ldsO1]); \
        sB0 += 32; sB1 += 32;                                                             \
    }                                                                                     \
    __builtin_amdgcn_s_setprio(1);                                                        \
    _Pragma("unroll") for (int i = 0; i < 8; ++i) {                                       \
        acc[i][2] = __builtin_amdgcn_mfma_f32_16x16x32_bf16(af[i], bfs[0], acc[i][2], 0, 0, 0); \
        acc[i][3] = __builtin_amdgcn_mfma_f32_16x16x32_bf16(af[i], bfs[1], acc[i][3], 0, 0, 0); \
    }                                                                                     \
    __builtin_amdgcn_s_setprio(0);                                                        \
    if (STAGE) asm volatile("s_waitcnt vmcnt(0)" ::: "memory");                           \
    __builtin_amdgcn_s_barrier();                                                         \
} while (0)

// Common address/offset setup for a 256x256 output tile
#define GEMM_SETUP(A_, W_, ldAW_, kOff_)                                                  \
    const int c0_ = tid, c1_ = 512 + tid;                                                 \
    const int rA0 = c0_ >> 2, ch0 = (c0_ & 3) ^ ((rA0 >> 1) & 3);                         \
    const int rA1 = c1_ >> 2, ch1 = (c1_ & 3) ^ ((rA1 >> 1) & 3);                         \
    const bf16_t* sA0 = (A_) + (size_t)(m0 + rA0) * (ldAW_) + (kOff_) + ch0 * 8;          \
    const bf16_t* sA1 = (A_) + (size_t)(m0 + rA1) * (ldAW_) + (kOff_) + ch1 * 8;          \
    const bf16_t* sB0 = (W_) + (size_t)(n0 + rA0) * (ldAW_) + (kOff_) + ch0 * 8;          \
    const bf16_t* sB1 = (W_) + (size_t)(n0 + rA1) * (ldAW_) + (kOff_) + ch1 * 8;          \
    const int ldsO0 = c0_ * 8, ldsO1 = c1_ * 8;                                           \
    int offA[8], offB[4];                                                                 \
    _Pragma("unroll") for (int i = 0; i < 8; ++i) {                                       \
        int row = wm * 128 + i * 16 + l15;                                                \
        offA[i] = row * 32 + ((lg ^ ((row >> 1) & 3)) * 8);                               \
    }                                                                                     \
    _Pragma("unroll") for (int j = 0; j < 4; ++j) {                                       \
        int row = wn * 64 + j * 16 + l15;                                                 \
        offB[j] = row * 32 + ((lg ^ ((row >> 1) & 3)) * 8);                               \
    }

// WO GEMM (fp32 out), ring-4, 128KB LDS, 256 blocks -> 1/CU spread
__global__ __launch_bounds__(512) void gemm256(const bf16_t* __restrict__ A,
                                               const bf16_t* __restrict__ W,
                                               float* __restrict__ C,
                                               int Nloc, int ldAW, int Kloc) {
    __shared__ __align__(16) bf16_t lds[4 * SLOT_E];
    const int tid = threadIdx.x;
    const int lane = tid & 63;
    const int w = tid >> 6;
    const int wm = w >> 2, wn = w & 3;
    const int l15 = lane & 15, lg = lane >> 4;
    const int nbx = Nloc >> 8;
    const int cpx = gridDim.x >> 3;
    const int bid = blockIdx.x;
    const int bid2 = (bid & 7) * cpx + (bid >> 3);
    const int m0 = (bid2 / nbx) * 256;
    const int n0 = (bid2 % nbx) * 256;
    GEMM_SETUP(A, W, ldAW, 0)
    #pragma unroll
    for (int tt = 0; tt < 3; ++tt) {
        const int ss = tt * SLOT_E;
        gload_lds16(sA0, &lds[ss + ldsO0]); gload_lds16(sA1, &lds[ss + ldsO1]);
        gload_lds16(sB0, &lds[ss + 8192 + ldsO0]); gload_lds16(sB1, &lds[ss + 8192 + ldsO1]);
        sA0 += 32; sA1 += 32; sB0 += 32; sB1 += 32;
    }
    asm volatile("s_waitcnt vmcnt(8)" ::: "memory");
    __builtin_amdgcn_s_barrier();
    f32x4 acc[8][4] = {};
    const int NT = Kloc >> 5;
    int t = 0;
    for (; t < NT - 3; ++t) GTILE(t, true, 8);
    GTILE(NT - 3, false, 4);
    GTILE(NT - 2, false, 0);
    GTILE(NT - 1, false, -1);
    #pragma unroll
    for (int i = 0; i < 8; ++i)
        #pragma unroll
        for (int jn = 0; jn < 4; ++jn)
            #pragma unroll
            for (int r = 0; r < 4; ++r) {
                int m = m0 + wm * 128 + i * 16 + lg * 4 + r;
                int n = n0 + wn * 64 + jn * 16 + l15;
                C[(size_t)m * Nloc + n] = acc[i][jn][r];
            }
}

// Fused QKV GEMM, ring-2 dbuf (64KB LDS -> 2 blocks/CU, 512 blocks = 512 slots, one round).
// blocks 0-255 = L1 (cols 0..4095, full K); 256-511 = L2 split-K
// (cols 4096..6143; z=0 -> QKVb+HID, z=1 -> P1 partial).
__global__ __launch_bounds__(512) void qkv256(const bf16_t* __restrict__ A,
                                              const bf16_t* __restrict__ Wfull,
                                              bf16_t* __restrict__ QKVb,
                                              bf16_t* __restrict__ P1) {
    __shared__ __align__(16) bf16_t lds[2 * SLOT_E];   // 64KB
    const int tid = threadIdx.x;
    const int lane = tid & 63;
    const int w = tid >> 6;
    const int wm = w >> 2, wn = w & 3;
    const int l15 = lane & 15, lg = lane >> 4;

    const int bid = blockIdx.x;
    const bf16_t* W; bf16_t* C; int ldC, kOff, Kloc, nbx, lb, cpx;
    if (bid < 256) {
        lb = bid; cpx = 32; nbx = 16;
        W = Wfull; kOff = 0; Kloc = HID;
        C = QKVb; ldC = QKV_N;
    } else {
        int b2 = bid - 256;
        const int z = b2 >> 7; b2 &= 127;
        lb = b2; cpx = 16; nbx = 8;
        W = Wfull + (size_t)HID * HID; kOff = z * 2048; Kloc = 2048;
        if (z) { C = P1; ldC = 2048; }
        else   { C = QKVb + HID; ldC = QKV_N; }
    }
    const int bid2 = (lb & 7) * cpx + (lb >> 3);
    const int m0 = (bid2 / nbx) * 256;
    const int n0 = (bid2 % nbx) * 256;
    GEMM_SETUP(A, W, HID, kOff)
    // prologue: stage tile 0 into slot 0, drain, barrier
    gload_lds16(sA0, &lds[ldsO0]); gload_lds16(sA1, &lds[ldsO1]);
    gload_lds16(sB0, &lds[8192 + ldsO0]); gload_lds16(sB1, &lds[8192 + ldsO1]);
    sA0 += 32; sA1 += 32; sB0 += 32; sB1 += 32;
    asm volatile("s_waitcnt vmcnt(0)" ::: "memory");
    __builtin_amdgcn_s_barrier();
    f32x4 acc[8][4] = {};
    const int NT = Kloc >> 5;
    int t = 0;
    for (; t < NT - 1; ++t) GTILE2(t, true);
    GTILE2(NT - 1, false);
    #pragma unroll
    for (int i = 0; i < 8; ++i)
        #pragma unroll
        for (int jn = 0; jn < 4; ++jn)
            #pragma unroll
            for (int r = 0; r < 4; ++r) {
                int m = m0 + wm * 128 + i * 16 + lg * 4 + r;
                int n = n0 + wn * 64 + jn * 16 + l15;
                ((bf16_t*)C)[(size_t)m * ldC + n] = (bf16_t)acc[i][jn][r];
            }
}

// ---------------- Fused split-K reduce + RoPE, vectorized (bf16x8 per half) ----------------
__global__ __launch_bounds__(256) void rope_fuse(bf16_t* __restrict__ QKV,
                                                 const bf16_t* __restrict__ P1,
                                                 const float* __restrict__ cosb,
                                                 const float* __restrict__ sinb) {
    int tid = blockIdx.x * blockDim.x + threadIdx.x;   // 4096*48*8 threads
    int d8 = (tid & 7) * 8;
    int hg = (tid >> 3) % 48;
    int bs = tid / (8 * 48);

    if (hg >= 40) {   // V region: split-K sum only
        int col = HID + NKV * HD + (hg - 40) * HD;
        bf16_t* rowp = QKV + (size_t)bs * QKV_N + col;
        const bf16_t* pp = P1 + (size_t)bs * 2048 + (col - HID);
        bf16x8 a0 = *(const bf16x8*)&rowp[d8];
        bf16x8 a1 = *(const bf16x8*)&rowp[d8 + 64];
        bf16x8 b0 = *(const bf16x8*)&pp[d8];
        bf16x8 b1 = *(const bf16x8*)&pp[d8 + 64];
        bf16x8 o0, o1;
        #pragma unroll
        for (int j = 0; j < 8; ++j) {
            o0[j] = (bf16_t)((float)a0[j] + (float)b0[j]);
            o1[j] = (bf16_t)((float)a1[j] + (float)b1[j]);
        }
        *(bf16x8*)&rowp[d8]      = o0;
        *(bf16x8*)&rowp[d8 + 64] = o1;
        return;
    }

    float x1[8], x2[8];
    bf16_t* rowp;
    float posc = 1.f;
    if (hg < 32) {    // Q: rope + pre-scale
        rowp = QKV + (size_t)bs * QKV_N + hg * HD;
        bf16x8 a0 = *(const bf16x8*)&rowp[d8];
        bf16x8 a1 = *(const bf16x8*)&rowp[d8 + 64];
        #pragma unroll
        for (int j = 0; j < 8; ++j) { x1[j] = (float)a0[j]; x2[j] = (float)a1[j]; }
        posc = QSCALE;
    } else {          // K: split-K sum + rope
        int col = HID + (hg - 32) * HD;
        rowp = QKV + (size_t)bs * QKV_N + col;
        const bf16_t* pp = P1 + (size_t)bs * 2048 + (col - HID);
        bf16x8 a0 = *(const bf16x8*)&rowp[d8];
        bf16x8 a1 = *(const bf16x8*)&rowp[d8 + 64];
        bf16x8 b0 = *(const bf16x8*)&pp[d8];
        bf16x8 b1 = *(const bf16x8*)&pp[d8 + 64];
        #pragma unroll
        for (int j = 0; j < 8; ++j) {
            x1[j] = (float)a0[j] + (float)b0[j];
            x2[j] = (float)a1[j] + (float)b1[j];
        }
    }
    const f32x4* cb = (const f32x4*)&cosb[(size_t)bs * HD + d8];
    const f32x4* sb = (const f32x4*)&sinb[(size_t)bs * HD + d8];
    f32x4 c1a = cb[0], c1b = cb[1], c2a = cb[16], c2b = cb[17];
    f32x4 s1a = sb[0], s1b = sb[1], s2a = sb[16], s2b = sb[17];
    float c1[8] = {c1a[0],c1a[1],c1a[2],c1a[3],c1b[0],c1b[1],c1b[2],c1b[3]};
    float s1[8] = {s1a[0],s1a[1],s1a[2],s1a[3],s1b[0],s1b[1],s1b[2],s1b[3]};
    float c2[8] = {c2a[0],c2a[1],c2a[2],c2a[3],c2b[0],c2b[1],c2b[2],c2b[3]};
    float s2[8] = {s2a[0],s2a[1],s2a[2],s2a[3],s2b[0],s2b[1],s2b[2],s2b[3]};
    bf16x8 o0, o1;
    #pragma unroll
    for (int j = 0; j < 8; ++j) {
        o0[j] = (bf16_t)((x1[j] * c1[j] - x2[j] * s1[j]) * posc);
        o1[j] = (bf16_t)((x2[j] * c2[j] + x1[j] * s2[j]) * posc);
    }
    *(bf16x8*)&rowp[d8]      = o0;
    *(bf16x8*)&rowp[d8 + 64] = o1;
}

// ---------------- Flash attention: GQA-merged, 8 waves = 4 heads x 64 q-rows ----------------
// Each wave owns 32 q-rows as TWO 16-row MFMA sets -> every K/V LDS fragment read feeds 2 MFMAs.
// Double-buffered K/V (one barrier per step). Grid 16x8x2 = 256 blocks = exactly 1/CU.
// XCD-aware remap: kvh = blockIdx.x & 7 pins each kv-head's 32 blocks to ONE XCD,
// so its 2MB K/V working set stays in that XCD's 4MB L2 (FETCH 139->25MB measured).
#define PITCH_P 72

__global__ __launch_bounds__(512) void attn_fwd(const bf16_t* __restrict__ QKV,
                                                bf16_t* __restrict__ O) {
    __shared__ __align__(16) bf16_t Kl[2][64 * 128];           // 32KB, chunk^=(k&7)
    __shared__ __align__(16) bf16_t Vt[2][128 * 64];           // 32KB, chunk^=(d&7)
    __shared__ __align__(16) bf16_t Pl[8][2][16 * PITCH_P];    // 36KB per-wave P (2 sets)
    const int tid = threadIdx.x;
    const int lane = tid & 63;
    const int w = tid >> 6;
    const int l15 = lane & 15, lg = lane >> 4;
    const int kvh = blockIdx.x & 7;
    const int pr = (blockIdx.x >> 3) + 2 * blockIdx.y;   // 0..15, bijective
    const int b = blockIdx.z;
    const int h = kvh * 4 + (w & 3);
    const int rg = w >> 2;

    int krow[2], kch[2];
    #pragma unroll
    for (int jj = 0; jj < 2; ++jj) { int q = jj * 512 + tid; krow[jj] = q >> 4; kch[jj] = q & 15; }
    const int k0v = (tid & 31) * 2;
    const int d0 = (tid >> 5) * 8;
    const int vci = k0v >> 3;
    const int vsub = k0v & 7;

    const bf16_t* Kb0 = QKV + (size_t)(b * S_LEN) * QKV_N + HID + kvh * HD;
    const bf16_t* Vb0 = QKV + (size_t)(b * S_LEN) * QKV_N + HID + NKV * HD + kvh * HD;
    bf16_t* Pl0 = Pl[w][0];
    bf16_t* Pl1 = Pl[w][1];

    for (int t = 0; t < 2; ++t) {
        const int qt = (t == 0) ? pr : (31 - pr);   // paired tiles -> 33 steps/block
        const int q0 = qt * 64;
        const int qb0 = q0 + rg * 32;
        const int qb1 = qb0 + 16;
        const int qrow0 = qb0 + l15, qrow1 = qb1 + l15;

        bf16x8 qf0[4], qf1[4];
        {
            const bf16_t* qp0 = QKV + (size_t)(b * S_LEN + qrow0) * QKV_N + h * HD;
            const bf16_t* qp1 = QKV + (size_t)(b * S_LEN + qrow1) * QKV_N + h * HD;
            #pragma unroll
            for (int c = 0; c < 4; ++c) {
                qf0[c] = *(const bf16x8*)&qp0[c * 32 + lg * 8];
                qf1[c] = *(const bf16x8*)&qp1[c * 32 + lg * 8];
            }
        }

        f32x4 acc0[8] = {}, acc1[8] = {};
        float mr0 = -INFF, lr0 = 0.f, mr1 = -INFF, lr1 = 0.f;
        const int nsteps = qt + 1;

        bf16x8 kst[2], vst[2];
        #pragma unroll
        for (int jj = 0; jj < 2; ++jj)
            kst[jj] = *(const bf16x8*)&Kb0[(size_t)krow[jj] * QKV_N + kch[jj] * 8];
        vst[0] = *(const bf16x8*)&Vb0[(size_t)(k0v + 0) * QKV_N + d0];
        vst[1] = *(const bf16x8*)&Vb0[(size_t)(k0v + 1) * QKV_N + d0];

        for (int st = 0; st < nsteps; ++st) {
            const int k0 = st * 64;
            const int p = st & 1;
            #pragma unroll
            for (int jj = 0; jj < 2; ++jj)
                *(bf16x8*)&Kl[p][krow[jj] * 128 + ((kch[jj] ^ (krow[jj] & 7)) * 8)] = kst[jj];
            #pragma unroll
            for (int j = 0; j < 8; ++j) {
                bf16x2 v2 = { vst[0][j], vst[1][j] };
                *(bf16x2*)&Vt[p][(d0 + j) * 64 + ((vci ^ j) << 3) + vsub] = v2;
            }
            __syncthreads();
            if (st + 1 < nsteps) {
                const bf16_t* Kb = Kb0 + (size_t)(k0 + 64) * QKV_N;
                const bf16_t* Vb = Vb0 + (size_t)(k0 + 64) * QKV_N;
                #pragma unroll
                for (int jj = 0; jj < 2; ++jj)
                    kst[jj] = *(const bf16x8*)&Kb[(size_t)krow[jj] * QKV_N + kch[jj] * 8];
                vst[0] = *(const bf16x8*)&Vb[(size_t)(k0v + 0) * QKV_N + d0];
                vst[1] = *(const bf16x8*)&Vb[(size_t)(k0v + 1) * QKV_N + d0];
            }
            f32x4 s0[4], s1[4];
            __builtin_amdgcn_s_setprio(1);
            #pragma unroll
            for (int nt = 0; nt < 4; ++nt) {
                s0[nt] = (f32x4){0.f, 0.f, 0.f, 0.f};
                s1[nt] = (f32x4){0.f, 0.f, 0.f, 0.f};
                const int row = nt * 16 + l15;
                const int rb = row * 128, key = row & 7;
                #pragma unroll
                for (int c = 0; c < 4; ++c) {
                    bf16x8 kf = *(const bf16x8*)&Kl[p][rb + (((c * 4 + lg) ^ key) * 8)];
                    s0[nt] = __builtin_amdgcn_mfma_f32_16x16x32_bf16(kf, qf0[c], s0[nt], 0, 0, 0);
                    s1[nt] = __builtin_amdgcn_mfma_f32_16x16x32_bf16(kf, qf1[c], s1[nt], 0, 0, 0);
                }
            }
            __builtin_amdgcn_s_setprio(0);
            if (k0 + 63 > qb0) {
                #pragma unroll
                for (int nt = 0; nt < 4; ++nt)
                    #pragma unroll
                    for (int r = 0; r < 4; ++r) {
                        int k = k0 + nt * 16 + lg * 4 + r;
                        if (k > qrow0) s0[nt][r] = -INFF;
                    }
            }
            if (k0 + 63 > qb1) {
                #pragma unroll
                for (int nt = 0; nt < 4; ++nt)
                    #pragma unroll
                    for (int r = 0; r < 4; ++r) {
                        int k = k0 + nt * 16 + lg * 4 + r;
                        if (k > qrow1) s1[nt][r] = -INFF;
                    }
            }
            // ---- softmax set0 ----
            {
                float ma = fmaxf(fmaxf(s0[0][0], s0[0][1]), fmaxf(s0[0][2], s0[0][3]));
                float mb = fmaxf(fmaxf(s0[1][0], s0[1][1]), fmaxf(s0[1][2], s0[1][3]));
                float mc = fmaxf(fmaxf(s0[2][0], s0[2][1]), fmaxf(s0[2][2], s0[2][3]));
                float md = fmaxf(fmaxf(s0[3][0], s0[3][1]), fmaxf(s0[3][2], s0[3][3]));
                float mx = fmaxf(fmaxf(ma, mb), fmaxf(mc, md));
                mx = fmaxf(mx, __shfl_xor(mx, 16));
                mx = fmaxf(mx, __shfl_xor(mx, 32));
                const bool nodefer = !__all(mx <= mr0 + 11.5f);
                const float mn = nodefer ? fmaxf(mr0, mx) : mr0;
                float sc = 1.f;
                if (nodefer) sc = exp2f(mr0 - mn);
                float rsum = 0.f;
                #pragma unroll
                for (int nt = 0; nt < 4; ++nt) {
                    float e0 = exp2f(s0[nt][0] - mn), e1 = exp2f(s0[nt][1] - mn);
                    float e2 = exp2f(s0[nt][2] - mn), e3 = exp2f(s0[nt][3] - mn);
                    s0[nt][0] = e0; s0[nt][1] = e1; s0[nt][2] = e2; s0[nt][3] = e3;
                    rsum += (e0 + e1) + (e2 + e3);
                }
                rsum += __shfl_xor(rsum, 16);
                rsum += __shfl_xor(rsum, 32);
                if (nodefer) { lr0 = lr0 * sc + rsum; mr0 = mn; }
                else         { lr0 += rsum; }
                #pragma unroll
                for (int nt = 0; nt < 4; ++nt) {
                    bf16x4 pk = {(bf16_t)s0[nt][0], (bf16_t)s0[nt][1], (bf16_t)s0[nt][2], (bf16_t)s0[nt][3]};
                    *(bf16x4*)&Pl0[l15 * PITCH_P + nt * 16 + lg * 4] = pk;
                }
                if (nodefer) {
                    float scb[4];
                    #pragma unroll
                    for (int r = 0; r < 4; ++r) scb[r] = __shfl(sc, lg * 4 + r);
                    #pragma unroll
                    for (int nt2 = 0; nt2 < 8; ++nt2)
                        #pragma unroll
                        for (int r = 0; r < 4; ++r) acc0[nt2][r] *= scb[r];
                }
            }
            // ---- softmax set1 ----
            {
                float ma = fmaxf(fmaxf(s1[0][0], s1[0][1]), fmaxf(s1[0][2], s1[0][3]));
                float mb = fmaxf(fmaxf(s1[1][0], s1[1][1]), fmaxf(s1[1][2], s1[1][3]));
                float mc = fmaxf(fmaxf(s1[2][0], s1[2][1]), fmaxf(s1[2][2], s1[2][3]));
                float md = fmaxf(fmaxf(s1[3][0], s1[3][1]), fmaxf(s1[3][2], s1[3][3]));
                float mx = fmaxf(fmaxf(ma, mb), fmaxf(mc, md));
                mx = fmaxf(mx, __shfl_xor(mx, 16));
                mx = fmaxf(mx, __shfl_xor(mx, 32));
                const bool nodefer = !__all(mx <= mr1 + 11.5f);
                const float mn = nodefer ? fmaxf(mr1, mx) : mr1;
                float sc = 1.f;
                if (nodefer) sc = exp2f(mr1 - mn);
                float rsum = 0.f;
                #pragma unroll
                for (int nt = 0; nt < 4; ++nt) {
                    float e0 = exp2f(s1[nt][0] - mn), e1 = exp2f(s1[nt][1] - mn);
                    float e2 = exp2f(s1[nt][2] - mn), e3 = exp2f(s1[nt][3] - mn);
                    s1[nt][0] = e0; s1[nt][1] = e1; s1[nt][2] = e2; s1[nt][3] = e3;
                    rsum += (e0 + e1) + (e2 + e3);
                }
                rsum += __shfl_xor(rsum, 16);
                rsum += __shfl_xor(rsum, 32);
                if (nodefer) { lr1 = lr1 * sc + rsum; mr1 = mn; }
                else         { lr1 += rsum; }
                #pragma unroll
                for (int nt = 0; nt < 4; ++nt) {
                    bf16x4 pk = {(bf16_t)s1[nt][0], (bf16_t)s1[nt][1], (bf16_t)s1[nt][2], (bf16_t)s1[nt][3]};
                    *(bf16x4*)&Pl1[l15 * PITCH_P + nt * 16 + lg * 4] = pk;
                }
                if (nodefer) {
                    float scb[4];
                    #pragma unroll
                    for (int r = 0; r < 4; ++r) scb[r] = __shfl(sc, lg * 4 + r);
                    #pragma unroll
                    for (int nt2 = 0; nt2 < 8; ++nt2)
                        #pragma unroll
                        for (int r = 0; r < 4; ++r) acc1[nt2][r] *= scb[r];
                }
            }
            // PV: each V fragment feeds BOTH q-sets
            __builtin_amdgcn_s_setprio(1);
            #pragma unroll
            for (int kc = 0; kc < 2; ++kc) {
                bf16x8 pf0 = *(const bf16x8*)&Pl0[l15 * PITCH_P + kc * 32 + lg * 8];
                bf16x8 pf1 = *(const bf16x8*)&Pl1[l15 * PITCH_P + kc * 32 + lg * 8];
                #pragma unroll
                for (int nt2 = 0; nt2 < 8; ++nt2) {
                    const int drow = nt2 * 16 + l15;
                    bf16x8 vf = *(const bf16x8*)&Vt[p][drow * 64 + (((kc * 4 + lg) ^ (drow & 7)) << 3)];
                    acc0[nt2] = __builtin_amdgcn_mfma_f32_16x16x32_bf16(pf0, vf, acc0[nt2], 0, 0, 0);
                    acc1[nt2] = __builtin_amdgcn_mfma_f32_16x16x32_bf16(pf1, vf, acc1[nt2], 0, 0, 0);
                }
            }
            __builtin_amdgcn_s_setprio(0);
        }
        float lb0[4], lb1[4];
        #pragma unroll
        for (int r = 0; r < 4; ++r) {
            lb0[r] = __builtin_amdgcn_rcpf(__shfl(lr0, lg * 4 + r));
            lb1[r] = __builtin_amdgcn_rcpf(__shfl(lr1, lg * 4 + r));
        }
        #pragma unroll
        for (int nt2 = 0; nt2 < 8; ++nt2)
            #pragma unroll
            for (int r = 0; r < 4; ++r) {
                int d = nt2 * 16 + l15;
                int qa = qb0 + lg * 4 + r;
                int qb = qb1 + lg * 4 + r;
                O[((size_t)(b * S_LEN + qa)) * (NH * HD) + h * HD + d] = (bf16_t)(acc0[nt2][r] * lb0[r]);
                O[((size_t)(b * S_LEN + qb)) * (NH * HD) + h * HD + d] = (bf16_t)(acc1[nt2][r] * lb1[r]);
            }
        __syncthreads();
    }
}

// ---------------- launch ----------------
extern "C" void kernel_launch(void* const* d_in, const int* in_sizes, int n_in,
                              void* d_out, int out_size, void* d_ws, size_t ws_size,
                              hipStream_t stream) {
    const float* hs   = (const float*)d_in[0];
    const float* cosb = (const float*)d_in[1];
    const float* sinb = (const float*)d_in[2];
    const float* wq   = (const float*)d_in[3];
    const float* wk   = (const float*)d_in[4];
    const float* wv   = (const float*)d_in[5];
    const float* wo   = (const float*)d_in[6];
    float* out = (float*)d_out;

    const size_t NHS = (size_t)B_SZ * S_LEN * HID;      // 16777216
    const size_t NKW = (size_t)NKV * HD * HID;          // 4194304
    const size_t NQKVW = (size_t)QKV_N * HID;           // 25165824
    size_t need = (NHS * 3 + NQKVW * 2) * sizeof(bf16_t);
    if (ws_size < need) return;

    bf16_t* p = (bf16_t*)d_ws;
    bf16_t* hsb  = p; p += NHS;     // [4096][4096]   } contiguous dst for f2b5:
    bf16_t* wqkv = p; p += NQKVW;   // [6144][4096]   }  hsb | wq | wk | wv | wob
    bf16_t* wob  = p; p += NHS;     // [4096][4096]   }
    bf16_t* QKVb = p; p += NQKVW;   // [4096][6144]
    bf16_t* Ab   = p; p += NHS;     // [4096][4096]; doubles as P1 [4096][2048] pre-attention
    bf16_t* P1   = Ab;

    // single fused convert: dst regions are contiguous starting at hsb
    const int n4_hs = (int)(NHS / 4), n4_kw = (int)(NKW / 4);
    const int c0 = n4_hs, c1 = c0 + n4_hs, c2 = c1 + n4_kw, c3 = c2 + n4_kw, c4 = c3 + n4_hs;
    f2b5<<<(c4 + 255) / 256, 256, 0, stream>>>((const float4*)hs, (const float4*)wq,
                                               (const float4*)wk, (const float4*)wv,
                                               (const float4*)wo, (bf16x4*)hsb,
                                               c0, c1, c2, c3, c4);

    // fused QKV projection (ring-2, 512 blocks co-resident at 2/CU)
    qkv256<<<512, 512, 0, stream>>>(hsb, wqkv, QKVb, P1);

    int rf_threads = B_SZ * S_LEN * 48 * 8;
    rope_fuse<<<rf_threads / 256, 256, 0, stream>>>(QKVb, P1, cosb, sinb);

    attn_fwd<<<dim3(16, NKV, B_SZ), 512, 0, stream>>>(QKVb, Ab);

    gemm256<<<256, 512, 0, stream>>>(Ab, wob, out, HID, HID, HID);
}

// Round 20
// 481.847 us; speedup vs baseline: 1.0424x; 1.0424x over previous
//
#include <hip/hip_runtime.h>
#include <stdint.h>

typedef __bf16 bf16_t;
typedef __bf16 bf16x8 __attribute__((ext_vector_type(8)));
typedef __bf16 bf16x4 __attribute__((ext_vector_type(4)));
typedef __bf16 bf16x2 __attribute__((ext_vector_type(2)));
typedef float f32x4 __attribute__((ext_vector_type(4)));

#define S_LEN 2048
#define NH 32
#define NKV 8
#define HD 128
#define B_SZ 2
#define HID 4096
#define QKV_N 6144
#define INFF __builtin_inff()
// 1/sqrt(128) * log2(e): Q pre-scaled so softmax uses exp2 directly
#define QSCALE (0.08838834764831845f * 1.4426950408889634f)

// global -> LDS direct copy, 16B per lane. LDS dest must be wave-uniform base + lane*16.
__device__ __forceinline__ void gload_lds16(const void* g, void* l) {
    __builtin_amdgcn_global_load_lds(
        (const __attribute__((address_space(1))) void*)(uintptr_t)g,
        (__attribute__((address_space(3))) void*)(uint32_t)(uintptr_t)l,
        16, 0, 0);
}

// ---------------- fp32 -> bf16 convert, 5 sources -> contiguous dst ----------------
__global__ __launch_bounds__(256) void f2b5(const float4* __restrict__ s0,
                                            const float4* __restrict__ s1,
                                            const float4* __restrict__ s2,
                                            const float4* __restrict__ s3,
                                            const float4* __restrict__ s4,
                                            bf16x4* __restrict__ dst,
                                            int c0, int c1, int c2, int c3, int c4) {
    int i = blockIdx.x * blockDim.x + threadIdx.x;
    if (i >= c4) return;
    const float4* s; int j;
    if (i < c0)      { s = s0; j = i; }
    else if (i < c1) { s = s1; j = i - c0; }
    else if (i < c2) { s = s2; j = i - c1; }
    else if (i < c3) { s = s3; j = i - c2; }
    else             { s = s4; j = i - c3; }
    float4 v = s[j];
    bf16x4 o = {(bf16_t)v.x, (bf16_t)v.y, (bf16_t)v.z, (bf16_t)v.w};
    dst[i] = o;
}

// ---------------- GEMM 256x256 tile, 8-wave, 4-slot ring, counted vmcnt ----------------
// One barrier per K-tile; ds_reads and MFMA clusters left unfenced so the compiler
// interleaves the LDS pipe under the MFMA pipe (they are separate HW pipes).
#define SLOT_E 16384   // elems per slot (A 8192 + B 8192)

#define GTILE(T, STAGE, VMW) do {                                                         \
    const int _sb = ((T) & 3) * SLOT_E;                                                   \
    const int _ss = (((T) + 3) & 3) * SLOT_E;                                             \
    bf16x8 af[8], bfr[2], bfs[2];                                                         \
    _Pragma("unroll") for (int i = 0; i < 8; ++i)                                         \
        af[i] = *(const bf16x8*)&lds[_sb + offA[i]];                                      \
    bfr[0] = *(const bf16x8*)&lds[_sb + 8192 + offB[0]];                                  \
    bfr[1] = *(const bf16x8*)&lds[_sb + 8192 + offB[1]];                                  \
    if (STAGE) {                                                                          \
        gload_lds16(sA0, &lds[_ss + ldsO0]); gload_lds16(sA1, &lds[_ss + ldsO1]);         \
        sA0 += 32; sA1 += 32;                                                             \
    }                                                                                     \
    __builtin_amdgcn_s_setprio(1);                                                        \
    _Pragma("unroll") for (int i = 0; i < 8; ++i) {                                       \
        acc[i][0] = __builtin_amdgcn_mfma_f32_16x16x32_bf16(af[i], bfr[0], acc[i][0], 0, 0, 0); \
        acc[i][1] = __builtin_amdgcn_mfma_f32_16x16x32_bf16(af[i], bfr[1], acc[i][1], 0, 0, 0); \
    }                                                                                     \
    __builtin_amdgcn_s_setprio(0);                                                        \
    bfs[0] = *(const bf16x8*)&lds[_sb + 8192 + offB[2]];                                  \
    bfs[1] = *(const bf16x8*)&lds[_sb + 8192 + offB[3]];                                  \
    if (STAGE) {                                                                          \
        gload_lds16(sB0, &lds[_ss + 8192 + ldsO0]); gload_lds16(sB1, &lds[_ss + 8192 + ldsO1]); \
        sB0 += 32; sB1 += 32;                                                             \
    }                                                                                     \
    __builtin_amdgcn_s_setprio(1);                                                        \
    _Pragma("unroll") for (int i = 0; i < 8; ++i) {                                       \
        acc[i][2] = __builtin_amdgcn_mfma_f32_16x16x32_bf16(af[i], bfs[0], acc[i][2], 0, 0, 0); \
        acc[i][3] = __builtin_amdgcn_mfma_f32_16x16x32_bf16(af[i], bfs[1], acc[i][3], 0, 0, 0); \
    }                                                                                     \
    __builtin_amdgcn_s_setprio(0);                                                        \
    if ((VMW) == 8)      asm volatile("s_waitcnt vmcnt(8)" ::: "memory");                 \
    else if ((VMW) == 4) asm volatile("s_waitcnt vmcnt(4)" ::: "memory");                 \
    else if ((VMW) == 0) asm volatile("s_waitcnt vmcnt(0)" ::: "memory");                 \
    __builtin_amdgcn_s_barrier();                                                         \
} while (0)

// Shared GEMM body (after role decode): computes C[m0..m0+255][n0..n0+255]
#define GEMM_BODY(A_, W_, Cv_, F32OUT_, ldC_, ldAW_, kOff_, Kloc_)                        \
    const int c0_ = tid, c1_ = 512 + tid;                                                 \
    const int rA0 = c0_ >> 2, ch0 = (c0_ & 3) ^ ((rA0 >> 1) & 3);                         \
    const int rA1 = c1_ >> 2, ch1 = (c1_ & 3) ^ ((rA1 >> 1) & 3);                         \
    const bf16_t* sA0 = (A_) + (size_t)(m0 + rA0) * (ldAW_) + (kOff_) + ch0 * 8;          \
    const bf16_t* sA1 = (A_) + (size_t)(m0 + rA1) * (ldAW_) + (kOff_) + ch1 * 8;          \
    const bf16_t* sB0 = (W_) + (size_t)(n0 + rA0) * (ldAW_) + (kOff_) + ch0 * 8;          \
    const bf16_t* sB1 = (W_) + (size_t)(n0 + rA1) * (ldAW_) + (kOff_) + ch1 * 8;          \
    const int ldsO0 = c0_ * 8, ldsO1 = c1_ * 8;                                           \
    int offA[8], offB[4];                                                                 \
    _Pragma("unroll") for (int i = 0; i < 8; ++i) {                                       \
        int row = wm * 128 + i * 16 + l15;                                                \
        offA[i] = row * 32 + ((lg ^ ((row >> 1) & 3)) * 8);                               \
    }                                                                                     \
    _Pragma("unroll") for (int j = 0; j < 4; ++j) {                                       \
        int row = wn * 64 + j * 16 + l15;                                                 \
        offB[j] = row * 32 + ((lg ^ ((row >> 1) & 3)) * 8);                               \
    }                                                                                     \
    _Pragma("unroll") for (int tt = 0; tt < 3; ++tt) {                                    \
        const int ss = tt * SLOT_E;                                                       \
        gload_lds16(sA0, &lds[ss + ldsO0]); gload_lds16(sA1, &lds[ss + ldsO1]);           \
        gload_lds16(sB0, &lds[ss + 8192 + ldsO0]); gload_lds16(sB1, &lds[ss + 8192 + ldsO1]); \
        sA0 += 32; sA1 += 32; sB0 += 32; sB1 += 32;                                       \
    }                                                                                     \
    asm volatile("s_waitcnt vmcnt(8)" ::: "memory");                                      \
    __builtin_amdgcn_s_barrier();                                                         \
    f32x4 acc[8][4] = {};                                                                 \
    const int NT = (Kloc_) >> 5;                                                          \
    int t = 0;                                                                            \
    for (; t < NT - 3; ++t) GTILE(t, true, 8);                                            \
    GTILE(NT - 3, false, 4);                                                              \
    GTILE(NT - 2, false, 0);                                                              \
    GTILE(NT - 1, false, -1);                                                             \
    _Pragma("unroll") for (int i = 0; i < 8; ++i)                                         \
        _Pragma("unroll") for (int jn = 0; jn < 4; ++jn)                                  \
            _Pragma("unroll") for (int r = 0; r < 4; ++r) {                               \
                int m = m0 + wm * 128 + i * 16 + lg * 4 + r;                              \
                int n = n0 + wn * 64 + jn * 16 + l15;                                     \
                float v = acc[i][jn][r];                                                  \
                if (F32OUT_) ((float*)(Cv_))[(size_t)m * (ldC_) + n] = v;                 \
                else         ((bf16_t*)(Cv_))[(size_t)m * (ldC_) + n] = (bf16_t)v;        \
            }

// WO GEMM (fp32 out)
__global__ __launch_bounds__(512) void gemm256(const bf16_t* __restrict__ A,
                                               const bf16_t* __restrict__ W,
                                               float* __restrict__ C,
                                               int Nloc, int ldAW, int Kloc) {
    __shared__ __align__(16) bf16_t lds[4 * SLOT_E];
    const int tid = threadIdx.x;
    const int lane = tid & 63;
    const int w = tid >> 6;
    const int wm = w >> 2, wn = w & 3;
    const int l15 = lane & 15, lg = lane >> 4;
    const int nbx = Nloc >> 8;
    const int cpx = gridDim.x >> 3;
    const int bid = blockIdx.x;
    const int bid2 = (bid & 7) * cpx + (bid >> 3);
    const int m0 = (bid2 / nbx) * 256;
    const int n0 = (bid2 % nbx) * 256;
    GEMM_BODY(A, W, C, true, Nloc, ldAW, 0, Kloc)
}

// Fused QKV GEMM: blocks 0-255 = L1 (cols 0..4095, full K); 256-511 = L2 split-K
// (cols 4096..6143; z=0 -> QKVb+HID, z=1 -> P1 partial).
__global__ __launch_bounds__(512) void qkv256(const bf16_t* __restrict__ A,
                                              const bf16_t* __restrict__ Wfull,
                                              bf16_t* __restrict__ QKVb,
                                              bf16_t* __restrict__ P1) {
    __shared__ __align__(16) bf16_t lds[4 * SLOT_E];
    const int tid = threadIdx.x;
    const int lane = tid & 63;
    const int w = tid >> 6;
    const int wm = w >> 2, wn = w & 3;
    const int l15 = lane & 15, lg = lane >> 4;

    const int bid = blockIdx.x;
    const bf16_t* W; bf16_t* C; int ldC, kOff, Kloc, nbx, lb, cpx;
    if (bid < 256) {
        lb = bid; cpx = 32; nbx = 16;
        W = Wfull; kOff = 0; Kloc = HID;
        C = QKVb; ldC = QKV_N;
    } else {
        int b2 = bid - 256;
        const int z = b2 >> 7; b2 &= 127;
        lb = b2; cpx = 16; nbx = 8;
        W = Wfull + (size_t)HID * HID; kOff = z * 2048; Kloc = 2048;
        if (z) { C = P1; ldC = 2048; }
        else   { C = QKVb + HID; ldC = QKV_N; }
    }
    const int bid2 = (lb & 7) * cpx + (lb >> 3);
    const int m0 = (bid2 / nbx) * 256;
    const int n0 = (bid2 % nbx) * 256;
    GEMM_BODY(A, W, C, false, ldC, HID, kOff, Kloc)
}

// ---------------- Fused split-K reduce + RoPE, vectorized (bf16x8 per half) ----------------
// Thread handles 8 consecutive d in [0,64) plus partners d+64 for one (bs, head-group).
__global__ __launch_bounds__(256) void rope_fuse(bf16_t* __restrict__ QKV,
                                                 const bf16_t* __restrict__ P1,
                                                 const float* __restrict__ cosb,
                                                 const float* __restrict__ sinb) {
    int tid = blockIdx.x * blockDim.x + threadIdx.x;   // 4096*48*8 threads
    int d8 = (tid & 7) * 8;
    int hg = (tid >> 3) % 48;
    int bs = tid / (8 * 48);

    if (hg >= 40) {   // V region: split-K sum only
        int col = HID + NKV * HD + (hg - 40) * HD;
        bf16_t* rowp = QKV + (size_t)bs * QKV_N + col;
        const bf16_t* pp = P1 + (size_t)bs * 2048 + (col - HID);
        bf16x8 a0 = *(const bf16x8*)&rowp[d8];
        bf16x8 a1 = *(const bf16x8*)&rowp[d8 + 64];
        bf16x8 b0 = *(const bf16x8*)&pp[d8];
        bf16x8 b1 = *(const bf16x8*)&pp[d8 + 64];
        bf16x8 o0, o1;
        #pragma unroll
        for (int j = 0; j < 8; ++j) {
            o0[j] = (bf16_t)((float)a0[j] + (float)b0[j]);
            o1[j] = (bf16_t)((float)a1[j] + (float)b1[j]);
        }
        *(bf16x8*)&rowp[d8]      = o0;
        *(bf16x8*)&rowp[d8 + 64] = o1;
        return;
    }

    float x1[8], x2[8];
    bf16_t* rowp;
    float posc = 1.f;
    if (hg < 32) {    // Q: rope + pre-scale
        rowp = QKV + (size_t)bs * QKV_N + hg * HD;
        bf16x8 a0 = *(const bf16x8*)&rowp[d8];
        bf16x8 a1 = *(const bf16x8*)&rowp[d8 + 64];
        #pragma unroll
        for (int j = 0; j < 8; ++j) { x1[j] = (float)a0[j]; x2[j] = (float)a1[j]; }
        posc = QSCALE;
    } else {          // K: split-K sum + rope
        int col = HID + (hg - 32) * HD;
        rowp = QKV + (size_t)bs * QKV_N + col;
        const bf16_t* pp = P1 + (size_t)bs * 2048 + (col - HID);
        bf16x8 a0 = *(const bf16x8*)&rowp[d8];
        bf16x8 a1 = *(const bf16x8*)&rowp[d8 + 64];
        bf16x8 b0 = *(const bf16x8*)&pp[d8];
        bf16x8 b1 = *(const bf16x8*)&pp[d8 + 64];
        #pragma unroll
        for (int j = 0; j < 8; ++j) {
            x1[j] = (float)a0[j] + (float)b0[j];
            x2[j] = (float)a1[j] + (float)b1[j];
        }
    }
    const f32x4* cb = (const f32x4*)&cosb[(size_t)bs * HD + d8];
    const f32x4* sb = (const f32x4*)&sinb[(size_t)bs * HD + d8];
    f32x4 c1a = cb[0], c1b = cb[1], c2a = cb[16], c2b = cb[17];
    f32x4 s1a = sb[0], s1b = sb[1], s2a = sb[16], s2b = sb[17];
    float c1[8] = {c1a[0],c1a[1],c1a[2],c1a[3],c1b[0],c1b[1],c1b[2],c1b[3]};
    float s1[8] = {s1a[0],s1a[1],s1a[2],s1a[3],s1b[0],s1b[1],s1b[2],s1b[3]};
    float c2[8] = {c2a[0],c2a[1],c2a[2],c2a[3],c2b[0],c2b[1],c2b[2],c2b[3]};
    float s2[8] = {s2a[0],s2a[1],s2a[2],s2a[3],s2b[0],s2b[1],s2b[2],s2b[3]};
    bf16x8 o0, o1;
    #pragma unroll
    for (int j = 0; j < 8; ++j) {
        o0[j] = (bf16_t)((x1[j] * c1[j] - x2[j] * s1[j]) * posc);
        o1[j] = (bf16_t)((x2[j] * c2[j] + x1[j] * s2[j]) * posc);
    }
    *(bf16x8*)&rowp[d8]      = o0;
    *(bf16x8*)&rowp[d8 + 64] = o1;
}

// ---------------- Flash attention: GQA-merged, 8 waves = 4 heads x 64 q-rows ----------------
// Each wave owns 32 q-rows as TWO 16-row MFMA sets -> every K/V LDS fragment read feeds 2 MFMAs.
// Double-buffered K/V (one barrier per step). Grid 16x8x2 = 256 blocks = exactly 1/CU.
// XCD-aware remap: kvh = blockIdx.x & 7 pins each kv-head's 32 blocks to ONE XCD,
// so its 2MB K/V working set stays in that XCD's 4MB L2 (FETCH 139->25MB measured).
#define PITCH_P 72

__global__ __launch_bounds__(512) void attn_fwd(const bf16_t* __restrict__ QKV,
                                                bf16_t* __restrict__ O) {
    __shared__ __align__(16) bf16_t Kl[2][64 * 128];           // 32KB, chunk^=(k&7)
    __shared__ __align__(16) bf16_t Vt[2][128 * 64];           // 32KB, chunk^=(d&7)
    __shared__ __align__(16) bf16_t Pl[8][2][16 * PITCH_P];    // 36KB per-wave P (2 sets)
    const int tid = threadIdx.x;
    const int lane = tid & 63;
    const int w = tid >> 6;
    const int l15 = lane & 15, lg = lane >> 4;
    const int kvh = blockIdx.x & 7;
    const int pr = (blockIdx.x >> 3) + 2 * blockIdx.y;   // 0..15, bijective
    const int b = blockIdx.z;
    const int h = kvh * 4 + (w & 3);
    const int rg = w >> 2;

    int krow[2], kch[2];
    #pragma unroll
    for (int jj = 0; jj < 2; ++jj) { int q = jj * 512 + tid; krow[jj] = q >> 4; kch[jj] = q & 15; }
    const int k0v = (tid & 31) * 2;
    const int d0 = (tid >> 5) * 8;
    const int vci = k0v >> 3;
    const int vsub = k0v & 7;

    const bf16_t* Kb0 = QKV + (size_t)(b * S_LEN) * QKV_N + HID + kvh * HD;
    const bf16_t* Vb0 = QKV + (size_t)(b * S_LEN) * QKV_N + HID + NKV * HD + kvh * HD;
    bf16_t* Pl0 = Pl[w][0];
    bf16_t* Pl1 = Pl[w][1];

    for (int t = 0; t < 2; ++t) {
        const int qt = (t == 0) ? pr : (31 - pr);   // paired tiles -> 33 steps/block
        const int q0 = qt * 64;
        const int qb0 = q0 + rg * 32;
        const int qb1 = qb0 + 16;
        const int qrow0 = qb0 + l15, qrow1 = qb1 + l15;

        bf16x8 qf0[4], qf1[4];
        {
            const bf16_t* qp0 = QKV + (size_t)(b * S_LEN + qrow0) * QKV_N + h * HD;
            const bf16_t* qp1 = QKV + (size_t)(b * S_LEN + qrow1) * QKV_N + h * HD;
            #pragma unroll
            for (int c = 0; c < 4; ++c) {
                qf0[c] = *(const bf16x8*)&qp0[c * 32 + lg * 8];
                qf1[c] = *(const bf16x8*)&qp1[c * 32 + lg * 8];
            }
        }

        f32x4 acc0[8] = {}, acc1[8] = {};
        float mr0 = -INFF, lr0 = 0.f, mr1 = -INFF, lr1 = 0.f;
        const int nsteps = qt + 1;

        bf16x8 kst[2], vst[2];
        #pragma unroll
        for (int jj = 0; jj < 2; ++jj)
            kst[jj] = *(const bf16x8*)&Kb0[(size_t)krow[jj] * QKV_N + kch[jj] * 8];
        vst[0] = *(const bf16x8*)&Vb0[(size_t)(k0v + 0) * QKV_N + d0];
        vst[1] = *(const bf16x8*)&Vb0[(size_t)(k0v + 1) * QKV_N + d0];

        for (int st = 0; st < nsteps; ++st) {
            const int k0 = st * 64;
            const int p = st & 1;
            #pragma unroll
            for (int jj = 0; jj < 2; ++jj)
                *(bf16x8*)&Kl[p][krow[jj] * 128 + ((kch[jj] ^ (krow[jj] & 7)) * 8)] = kst[jj];
            #pragma unroll
            for (int j = 0; j < 8; ++j) {
                bf16x2 v2 = { vst[0][j], vst[1][j] };
                *(bf16x2*)&Vt[p][(d0 + j) * 64 + ((vci ^ j) << 3) + vsub] = v2;
            }
            __syncthreads();
            if (st + 1 < nsteps) {
                const bf16_t* Kb = Kb0 + (size_t)(k0 + 64) * QKV_N;
                const bf16_t* Vb = Vb0 + (size_t)(k0 + 64) * QKV_N;
                #pragma unroll
                for (int jj = 0; jj < 2; ++jj)
                    kst[jj] = *(const bf16x8*)&Kb[(size_t)krow[jj] * QKV_N + kch[jj] * 8];
                vst[0] = *(const bf16x8*)&Vb[(size_t)(k0v + 0) * QKV_N + d0];
                vst[1] = *(const bf16x8*)&Vb[(size_t)(k0v + 1) * QKV_N + d0];
            }
            f32x4 s0[4], s1[4];
            __builtin_amdgcn_s_setprio(1);
            #pragma unroll
            for (int nt = 0; nt < 4; ++nt) {
                s0[nt] = (f32x4){0.f, 0.f, 0.f, 0.f};
                s1[nt] = (f32x4){0.f, 0.f, 0.f, 0.f};
                const int row = nt * 16 + l15;
                const int rb = row * 128, key = row & 7;
                #pragma unroll
                for (int c = 0; c < 4; ++c) {
                    bf16x8 kf = *(const bf16x8*)&Kl[p][rb + (((c * 4 + lg) ^ key) * 8)];
                    s0[nt] = __builtin_amdgcn_mfma_f32_16x16x32_bf16(kf, qf0[c], s0[nt], 0, 0, 0);
                    s1[nt] = __builtin_amdgcn_mfma_f32_16x16x32_bf16(kf, qf1[c], s1[nt], 0, 0, 0);
                }
            }
            __builtin_amdgcn_s_setprio(0);
            if (k0 + 63 > qb0) {
                #pragma unroll
                for (int nt = 0; nt < 4; ++nt)
                    #pragma unroll
                    for (int r = 0; r < 4; ++r) {
                        int k = k0 + nt * 16 + lg * 4 + r;
                        if (k > qrow0) s0[nt][r] = -INFF;
                    }
            }
            if (k0 + 63 > qb1) {
                #pragma unroll
                for (int nt = 0; nt < 4; ++nt)
                    #pragma unroll
                    for (int r = 0; r < 4; ++r) {
                        int k = k0 + nt * 16 + lg * 4 + r;
                        if (k > qrow1) s1[nt][r] = -INFF;
                    }
            }
            // ---- softmax set0 ----
            {
                float ma = fmaxf(fmaxf(s0[0][0], s0[0][1]), fmaxf(s0[0][2], s0[0][3]));
                float mb = fmaxf(fmaxf(s0[1][0], s0[1][1]), fmaxf(s0[1][2], s0[1][3]));
                float mc = fmaxf(fmaxf(s0[2][0], s0[2][1]), fmaxf(s0[2][2], s0[2][3]));
                float md = fmaxf(fmaxf(s0[3][0], s0[3][1]), fmaxf(s0[3][2], s0[3][3]));
                float mx = fmaxf(fmaxf(ma, mb), fmaxf(mc, md));
                mx = fmaxf(mx, __shfl_xor(mx, 16));
                mx = fmaxf(mx, __shfl_xor(mx, 32));
                const bool nodefer = !__all(mx <= mr0 + 11.5f);
                const float mn = nodefer ? fmaxf(mr0, mx) : mr0;
                float sc = 1.f;
                if (nodefer) sc = exp2f(mr0 - mn);
                float rsum = 0.f;
                #pragma unroll
                for (int nt = 0; nt < 4; ++nt) {
                    float e0 = exp2f(s0[nt][0] - mn), e1 = exp2f(s0[nt][1] - mn);
                    float e2 = exp2f(s0[nt][2] - mn), e3 = exp2f(s0[nt][3] - mn);
                    s0[nt][0] = e0; s0[nt][1] = e1; s0[nt][2] = e2; s0[nt][3] = e3;
                    rsum += (e0 + e1) + (e2 + e3);
                }
                rsum += __shfl_xor(rsum, 16);
                rsum += __shfl_xor(rsum, 32);
                if (nodefer) { lr0 = lr0 * sc + rsum; mr0 = mn; }
                else         { lr0 += rsum; }
                #pragma unroll
                for (int nt = 0; nt < 4; ++nt) {
                    bf16x4 pk = {(bf16_t)s0[nt][0], (bf16_t)s0[nt][1], (bf16_t)s0[nt][2], (bf16_t)s0[nt][3]};
                    *(bf16x4*)&Pl0[l15 * PITCH_P + nt * 16 + lg * 4] = pk;
                }
                if (nodefer) {
                    float scb[4];
                    #pragma unroll
                    for (int r = 0; r < 4; ++r) scb[r] = __shfl(sc, lg * 4 + r);
                    #pragma unroll
                    for (int nt2 = 0; nt2 < 8; ++nt2)
                        #pragma unroll
                        for (int r = 0; r < 4; ++r) acc0[nt2][r] *= scb[r];
                }
            }
            // ---- softmax set1 ----
            {
                float ma = fmaxf(fmaxf(s1[0][0], s1[0][1]), fmaxf(s1[0][2], s1[0][3]));
                float mb = fmaxf(fmaxf(s1[1][0], s1[1][1]), fmaxf(s1[1][2], s1[1][3]));
                float mc = fmaxf(fmaxf(s1[2][0], s1[2][1]), fmaxf(s1[2][2], s1[2][3]));
                float md = fmaxf(fmaxf(s1[3][0], s1[3][1]), fmaxf(s1[3][2], s1[3][3]));
                float mx = fmaxf(fmaxf(ma, mb), fmaxf(mc, md));
                mx = fmaxf(mx, __shfl_xor(mx, 16));
                mx = fmaxf(mx, __shfl_xor(mx, 32));
                const bool nodefer = !__all(mx <= mr1 + 11.5f);
                const float mn = nodefer ? fmaxf(mr1, mx) : mr1;
                float sc = 1.f;
                if (nodefer) sc = exp2f(mr1 - mn);
                float rsum = 0.f;
                #pragma unroll
                for (int nt = 0; nt < 4; ++nt) {
                    float e0 = exp2f(s1[nt][0] - mn), e1 = exp2f(s1[nt][1] - mn);
                    float e2 = exp2f(s1[nt][2] - mn), e3 = exp2f(s1[nt][3] - mn);
                    s1[nt][0] = e0; s1[nt][1] = e1; s1[nt][2] = e2; s1[nt][3] = e3;
                    rsum += (e0 + e1) + (e2 + e3);
                }
                rsum += __shfl_xor(rsum, 16);
                rsum += __shfl_xor(rsum, 32);
                if (nodefer) { lr1 = lr1 * sc + rsum; mr1 = mn; }
                else         { lr1 += rsum; }
                #pragma unroll
                for (int nt = 0; nt < 4; ++nt) {
                    bf16x4 pk = {(bf16_t)s1[nt][0], (bf16_t)s1[nt][1], (bf16_t)s1[nt][2], (bf16_t)s1[nt][3]};
                    *(bf16x4*)&Pl1[l15 * PITCH_P + nt * 16 + lg * 4] = pk;
                }
                if (nodefer) {
                    float scb[4];
                    #pragma unroll
                    for (int r = 0; r < 4; ++r) scb[r] = __shfl(sc, lg * 4 + r);
                    #pragma unroll
                    for (int nt2 = 0; nt2 < 8; ++nt2)
                        #pragma unroll
                        for (int r = 0; r < 4; ++r) acc1[nt2][r] *= scb[r];
                }
            }
            // PV: each V fragment feeds BOTH q-sets
            __builtin_amdgcn_s_setprio(1);
            #pragma unroll
            for (int kc = 0; kc < 2; ++kc) {
                bf16x8 pf0 = *(const bf16x8*)&Pl0[l15 * PITCH_P + kc * 32 + lg * 8];
                bf16x8 pf1 = *(const bf16x8*)&Pl1[l15 * PITCH_P + kc * 32 + lg * 8];
                #pragma unroll
                for (int nt2 = 0; nt2 < 8; ++nt2) {
                    const int drow = nt2 * 16 + l15;
                    bf16x8 vf = *(const bf16x8*)&Vt[p][drow * 64 + (((kc * 4 + lg) ^ (drow & 7)) << 3)];
                    acc0[nt2] = __builtin_amdgcn_mfma_f32_16x16x32_bf16(pf0, vf, acc0[nt2], 0, 0, 0);
                    acc1[nt2] = __builtin_amdgcn_mfma_f32_16x16x32_bf16(pf1, vf, acc1[nt2], 0, 0, 0);
                }
            }
            __builtin_amdgcn_s_setprio(0);
        }
        float lb0[4], lb1[4];
        #pragma unroll
        for (int r = 0; r < 4; ++r) {
            lb0[r] = __builtin_amdgcn_rcpf(__shfl(lr0, lg * 4 + r));
            lb1[r] = __builtin_amdgcn_rcpf(__shfl(lr1, lg * 4 + r));
        }
        #pragma unroll
        for (int nt2 = 0; nt2 < 8; ++nt2)
            #pragma unroll
            for (int r = 0; r < 4; ++r) {
                int d = nt2 * 16 + l15;
                int qa = qb0 + lg * 4 + r;
                int qb = qb1 + lg * 4 + r;
                O[((size_t)(b * S_LEN + qa)) * (NH * HD) + h * HD + d] = (bf16_t)(acc0[nt2][r] * lb0[r]);
                O[((size_t)(b * S_LEN + qb)) * (NH * HD) + h * HD + d] = (bf16_t)(acc1[nt2][r] * lb1[r]);
            }
        __syncthreads();
    }
}

// ---------------- launch ----------------
extern "C" void kernel_launch(void* const* d_in, const int* in_sizes, int n_in,
                              void* d_out, int out_size, void* d_ws, size_t ws_size,
                              hipStream_t stream) {
    const float* hs   = (const float*)d_in[0];
    const float* cosb = (const float*)d_in[1];
    const float* sinb = (const float*)d_in[2];
    const float* wq   = (const float*)d_in[3];
    const float* wk   = (const float*)d_in[4];
    const float* wv   = (const float*)d_in[5];
    const float* wo   = (const float*)d_in[6];
    float* out = (float*)d_out;

    const size_t NHS = (size_t)B_SZ * S_LEN * HID;      // 16777216
    const size_t NKW = (size_t)NKV * HD * HID;          // 4194304
    const size_t NQKVW = (size_t)QKV_N * HID;           // 25165824
    size_t need = (NHS * 3 + NQKVW * 2) * sizeof(bf16_t);
    if (ws_size < need) return;

    bf16_t* p = (bf16_t*)d_ws;
    bf16_t* hsb  = p; p += NHS;     // [4096][4096]   } contiguous dst for f2b5:
    bf16_t* wqkv = p; p += NQKVW;   // [6144][4096]   }  hsb | wq | wk | wv | wob
    bf16_t* wob  = p; p += NHS;     // [4096][4096]   }
    bf16_t* QKVb = p; p += NQKVW;   // [4096][6144]
    bf16_t* Ab   = p; p += NHS;     // [4096][4096]; doubles as P1 [4096][2048] pre-attention
    bf16_t* P1   = Ab;

    // single fused convert: dst regions are contiguous starting at hsb
    const int n4_hs = (int)(NHS / 4), n4_kw = (int)(NKW / 4);
    const int c0 = n4_hs, c1 = c0 + n4_hs, c2 = c1 + n4_kw, c3 = c2 + n4_kw, c4 = c3 + n4_hs;
    f2b5<<<(c4 + 255) / 256, 256, 0, stream>>>((const float4*)hs, (const float4*)wq,
                                               (const float4*)wk, (const float4*)wv,
                                               (const float4*)wo, (bf16x4*)hsb,
                                               c0, c1, c2, c3, c4);

    // fused QKV projection (L1 full-K + L2 split-K in one dispatch)
    qkv256<<<512, 512, 0, stream>>>(hsb, wqkv, QKVb, P1);

    int rf_threads = B_SZ * S_LEN * 48 * 8;
    rope_fuse<<<rf_threads / 256, 256, 0, stream>>>(QKVb, P1, cosb, sinb);

    attn_fwd<<<dim3(16, NKV, B_SZ), 512, 0, stream>>>(QKVb, Ab);

    gemm256<<<256, 512, 0, stream>>>(Ab, wob, out, HID, HID, HID);
}